// Round 1
// baseline (344.159 us; speedup 1.0000x reference)
//
#include <hip/hip_runtime.h>
#include <hip/hip_bf16.h>

using u16 = unsigned short;

typedef __bf16 bf16x8 __attribute__((ext_vector_type(8)));
typedef float  f32x4  __attribute__((ext_vector_type(4)));

__device__ __forceinline__ float b2f(u16 u) {
  union { unsigned u; float f; } v; v.u = ((unsigned)u) << 16; return v.f;
}
__device__ __forceinline__ u16 f2b(float f) {
  union { float f; unsigned u; } v; v.f = f;
  unsigned r = v.u + 0x7fffu + ((v.u >> 16) & 1u);
  return (u16)(r >> 16);
}

// async global->LDS, 16B per lane. LDS dest must be uniform base + lane*16.
__device__ __forceinline__ void gld_lds16(const void* g, void* l) {
  __builtin_amdgcn_global_load_lds(
      (__attribute__((address_space(1))) void*)(unsigned long long)(g),
      (__attribute__((address_space(3))) void*)(unsigned long long)(l),
      16, 0, 0);
}

// ---------------------------------------------------------------------------
// Generic NT GEMM: C[m,n] = sum_k A[m,k] * B[n,k], bf16 in, fp32 acc.
// Block tile 128x128, 4 waves (2x2), wave = 4x4 of 16x16x32 MFMA.
// Retained for the small per-(b,h) GEMMs (kv / causal-A / A@V, EPI 1..3).
// ---------------------------------------------------------------------------
template <int EPI, int BK>
__global__ __launch_bounds__(256) void gemm_bt(
    const u16* __restrict__ A, int lda, long sA1, long sA2,
    const u16* __restrict__ B, int ldb, long sB1, long sB2,
    void* __restrict__ Cv, int ldc, long sC1, long sC2,
    int K, int HDIV,
    const float* __restrict__ bias, const float* __restrict__ resid,
    float* __restrict__ partOut) {
  __shared__ __align__(16) u16 lds[2 * 128 * BK];
  __shared__ float denS[128];
  const int t = threadIdx.x;
  const int lane = t & 63;
  const int wave = t >> 6;
  const int wm = wave >> 1, wn = wave & 1;
  const int laneM = lane & 15, quad = lane >> 4;
  const int zb = blockIdx.z / HDIV, zh = blockIdx.z % HDIV;

  int bx = blockIdx.x, by = blockIdx.y;
  if (EPI == 2) { by = (bx >= 1) ? 1 : 0; bx = (bx == 2) ? 1 : 0; }
  const int kEnd = (EPI == 3) ? ((by + 1) * 128 < K ? (by + 1) * 128 : K) : K;

  const u16* Abase = A + zb * sA1 + zh * sA2 + (long)by * 128 * lda;
  const u16* Bbase = B + zb * sB1 + zh * sB2 + (long)bx * 128 * ldb;

  constexpr int STEPS = BK / 16;   // staging steps per operand (2048 elem each)
  constexpr int RPS = 2048 / BK;   // rows per staging step
  constexpr int KK = BK / 32;      // MFMA k-steps per LDS tile
  const int sRow = (BK == 64) ? (t >> 3) : (t >> 2);
  const int sg = (BK == 64) ? (t & 7) : (t & 3);
  const int swz = (BK == 64) ? (sg ^ (sRow & 7)) : (sg ^ ((sRow >> 1) & 3));
  const int sc = swz * 8;  // swizzled global k-chunk offset (elems)

  f32x4 acc[4][4];
#pragma unroll
  for (int i = 0; i < 4; ++i)
#pragma unroll
    for (int j = 0; j < 4; ++j) acc[i][j] = (f32x4){0.f, 0.f, 0.f, 0.f};
  float dsum[4] = {0.f, 0.f, 0.f, 0.f};

  for (int k0 = 0; k0 < kEnd; k0 += BK) {
#pragma unroll
    for (int p = 0; p < STEPS; ++p)
      gld_lds16(Abase + (long)(p * RPS + sRow) * lda + k0 + sc,
                &lds[p * 2048 + t * 8]);
#pragma unroll
    for (int p = 0; p < STEPS; ++p)
      gld_lds16(Bbase + (long)(p * RPS + sRow) * ldb + k0 + sc,
                &lds[128 * BK + p * 2048 + t * 8]);
    __syncthreads();  // drains vmcnt(0): LDS staging complete
    bf16x8 af[KK][4], bfv[KK][4];
#pragma unroll
    for (int kk = 0; kk < KK; ++kk) {
      int perm8;
      if (BK == 64) perm8 = ((kk * 4 + quad) ^ (laneM & 7)) * 8;
      else          perm8 = (quad ^ ((laneM >> 1) & 3)) * 8;
#pragma unroll
      for (int i = 0; i < 4; ++i) {
        af[kk][i] = *(const bf16x8*)&lds[(wm * 64 + i * 16 + laneM) * BK + perm8];
        bfv[kk][i] =
            *(const bf16x8*)&lds[128 * BK + (wn * 64 + i * 16 + laneM) * BK + perm8];
      }
    }
    if (EPI == 3) {  // rowsum of A from fragments (den; mask is pre-applied)
#pragma unroll
      for (int kk = 0; kk < KK; ++kk)
#pragma unroll
        for (int i = 0; i < 4; ++i) {
          union { bf16x8 v; u16 s[8]; } u; u.v = af[kk][i];
          float ds = 0.f;
#pragma unroll
          for (int e = 0; e < 8; ++e) ds += b2f(u.s[e]);
          dsum[i] += ds;
        }
    }
#pragma unroll
    for (int kk = 0; kk < KK; ++kk)
#pragma unroll
      for (int i = 0; i < 4; ++i)
#pragma unroll
        for (int j = 0; j < 4; ++j)
          acc[i][j] = __builtin_amdgcn_mfma_f32_16x16x32_bf16(
              af[kk][i], bfv[kk][j], acc[i][j], 0, 0, 0);
    __syncthreads();  // all waves done reading before next stage
  }

  if (EPI == 3) {
#pragma unroll
    for (int i = 0; i < 4; ++i) {
      float s = dsum[i];
      s += __shfl_xor(s, 16);
      s += __shfl_xor(s, 32);
      if (wn == 0 && quad == 0)
        denS[wm * 64 + i * 16 + laneM] = fmaxf(s, 1e-8f);
    }
    __syncthreads();
  }

  if (EPI == 1) {  // column sums of tile -> part[zh*256 + col] (cs fusion)
#pragma unroll
    for (int j = 0; j < 4; ++j) {
      float s = 0.f;
#pragma unroll
      for (int i = 0; i < 4; ++i)
#pragma unroll
        for (int r = 0; r < 4; ++r) s += acc[i][j][r];
      s += __shfl_xor(s, 16);
      s += __shfl_xor(s, 32);
      if (quad == 0)
        atomicAdd(&partOut[zh * 256 + bx * 128 + wn * 64 + j * 16 + laneM], s);
    }
  }

  const long cOff = zb * sC1 + zh * sC2;
  const int colB = bx * 128 + wn * 64;
#pragma unroll
  for (int i = 0; i < 4; ++i) {
#pragma unroll
    for (int j = 0; j < 4; ++j) {
#pragma unroll
      for (int r = 0; r < 4; ++r) {
        const int lrow = wm * 64 + i * 16 + quad * 4 + r;  // row within block
        const int row = by * 128 + lrow;                   // within-batch row
        const int col = colB + j * 16 + laneM;             // within-batch col
        const long idx = cOff + (long)row * ldc + col;
        float v = acc[i][j][r];
        if (EPI == 0 || EPI == 1) {
          ((u16*)Cv)[idx] = f2b(v);
        } else if (EPI == 2) {
          ((u16*)Cv)[idx] = f2b(col <= row ? v : 0.0f);
        } else if (EPI == 3) {
          ((u16*)Cv)[idx] = f2b(v / denS[lrow]);
        } else {
          ((float*)Cv)[idx] =
              (zb == 0) ? v + bias[col] + resid[(long)row * ldc + col] : v;
        }
      }
    }
  }
}

// ---------------------------------------------------------------------------
// 256x256 NT GEMM, counted-vmcnt phase schedule (T2+T3+T4+T5 port).
// 512 threads = 8 waves (2 M x 4 N); per-wave 128x64 output = 8x4 16x16 frags.
// BK=32 K-tiles, TRIPLE-buffered LDS (3 x 16KB per operand = 96KB total):
//   iteration tau reads buf tau%3 and stages tile tau+2 into buf (tau+2)%3 —
//   that buffer's data (tile tau-1) was fully consumed an iteration ago, so
//   staging loads may stay in flight across barriers (no vmcnt(0) drain).
// Per K-tile: 2 phases (m-half each):
//   {ds_read frags; issue 2 global_load_lds; s_barrier; lgkmcnt(0);
//    setprio(1); 16 MFMA; setprio(0)}  — one s_waitcnt vmcnt(4) per K-tile.
// Swizzle identical to gemm_bt BK=32 (proven): stage chunk g of row r holds
// global chunk g^((r>>1)&3); read granule quad^((laneM>>1)&3). 2-way bank
// aliasing only (free, m136).
// Grid: flat nbx*nby*Z with nbx=nby=8; bijective chunked XCD swizzle
// (grid%8==0) so each XCD L2 reuses one A row-panel across all 8 bx.
// EPI 0: bf16 out (proj). EPI 4: fp32 out, z==0 adds bias+resid (Wo splitK).
// ---------------------------------------------------------------------------
template <int EPI>
__global__ __launch_bounds__(512) void gemm256(
    const u16* __restrict__ A, int lda, long sA1,
    const u16* __restrict__ B, int ldb, long sB1,
    void* __restrict__ Cv, int ldc, long sC1, int K,
    const float* __restrict__ bias, const float* __restrict__ resid) {
  __shared__ __align__(16) u16 ldsA[3][8192];
  __shared__ __align__(16) u16 ldsB[3][8192];
  const int t = threadIdx.x;
  const int lane = t & 63, wave = t >> 6;
  const int wm = wave >> 2, wn = wave & 3;
  const int laneM = lane & 15, quad = lane >> 4;

  const int cpx = gridDim.x >> 3;                      // blocks per XCD chunk
  const int id2 = (blockIdx.x & 7) * cpx + (blockIdx.x >> 3);
  const int bx = id2 & 7, by = (id2 >> 3) & 7, z = id2 >> 6;

  const u16* Ag = A + (long)z * sA1 + (long)by * 256 * lda;
  const u16* Bg = B + (long)z * sB1 + (long)bx * 256 * ldb;

  const int nt = K >> 5;                               // K-tiles of 32
  const int rg = (quad ^ ((laneM >> 1) & 3)) * 8;      // read-granule offset
  const int rowA = wm * 128 + laneM;
  const int rowB = wn * 64 + laneM;

  f32x4 acc[8][4];
#pragma unroll
  for (int i = 0; i < 8; ++i)
#pragma unroll
    for (int j = 0; j < 4; ++j) acc[i][j] = (f32x4){0.f, 0.f, 0.f, 0.f};

  // prologue: stage tiles 0 and 1 (4 loads/wave each); wait only for tile 0
  { // stage helper inlined: 2 x 16B per thread per operand per tile
#pragma unroll
    for (int p = 0; p < 2; ++p) {
      const int chunk = p * 512 + t, row = chunk >> 2;
      const int c = (chunk & 3) ^ ((row >> 1) & 3);
      gld_lds16(Ag + row * lda + c * 8, &ldsA[0][chunk * 8]);
    }
#pragma unroll
    for (int p = 0; p < 2; ++p) {
      const int chunk = p * 512 + t, row = chunk >> 2;
      const int c = (chunk & 3) ^ ((row >> 1) & 3);
      gld_lds16(Bg + row * ldb + c * 8, &ldsB[0][chunk * 8]);
    }
#pragma unroll
    for (int p = 0; p < 2; ++p) {
      const int chunk = p * 512 + t, row = chunk >> 2;
      const int c = (chunk & 3) ^ ((row >> 1) & 3);
      gld_lds16(Ag + row * lda + 32 + c * 8, &ldsA[1][chunk * 8]);
    }
#pragma unroll
    for (int p = 0; p < 2; ++p) {
      const int chunk = p * 512 + t, row = chunk >> 2;
      const int c = (chunk & 3) ^ ((row >> 1) & 3);
      gld_lds16(Bg + row * ldb + 32 + c * 8, &ldsB[1][chunk * 8]);
    }
  }
  asm volatile("s_waitcnt vmcnt(4)" ::: "memory");
  __builtin_amdgcn_s_barrier();

  int buf = 0, sbuf = 2;
  for (int tau = 0; tau < nt; ++tau) {
    const u16* la = &ldsA[buf][0];
    const u16* lb = &ldsB[buf][0];
    const bool st = (tau + 2) < nt;
    const int ks = (tau + 2) << 5;
    bf16x8 af[4], bv[4];

    // ---- phase 1: frags for C rows m0-3 + all B; stage A of tile tau+2 ----
#pragma unroll
    for (int m = 0; m < 4; ++m)
      af[m] = *(const bf16x8*)&la[(rowA + m * 16) * 32 + rg];
#pragma unroll
    for (int n = 0; n < 4; ++n)
      bv[n] = *(const bf16x8*)&lb[(rowB + n * 16) * 32 + rg];
    if (st) {
#pragma unroll
      for (int p = 0; p < 2; ++p) {
        const int chunk = p * 512 + t, row = chunk >> 2;
        const int c = (chunk & 3) ^ ((row >> 1) & 3);
        gld_lds16(Ag + row * lda + ks + c * 8, &ldsA[sbuf][chunk * 8]);
      }
    }
    __builtin_amdgcn_s_barrier();
    asm volatile("s_waitcnt lgkmcnt(0)" ::: "memory");
    __builtin_amdgcn_s_setprio(1);
#pragma unroll
    for (int m = 0; m < 4; ++m)
#pragma unroll
      for (int n = 0; n < 4; ++n)
        acc[m][n] = __builtin_amdgcn_mfma_f32_16x16x32_bf16(af[m], bv[n],
                                                            acc[m][n], 0, 0, 0);
    __builtin_amdgcn_s_setprio(0);
    __builtin_amdgcn_s_barrier();

    // ---- phase 2: frags for C rows m4-7; stage B of tile tau+2 ----
#pragma unroll
    for (int m = 0; m < 4; ++m)
      af[m] = *(const bf16x8*)&la[(rowA + 64 + m * 16) * 32 + rg];
    if (st) {
#pragma unroll
      for (int p = 0; p < 2; ++p) {
        const int chunk = p * 512 + t, row = chunk >> 2;
        const int c = (chunk & 3) ^ ((row >> 1) & 3);
        gld_lds16(Bg + row * ldb + ks + c * 8, &ldsB[sbuf][chunk * 8]);
      }
    }
    __builtin_amdgcn_s_barrier();
    asm volatile("s_waitcnt lgkmcnt(0)" ::: "memory");
    __builtin_amdgcn_s_setprio(1);
#pragma unroll
    for (int m = 0; m < 4; ++m)
#pragma unroll
      for (int n = 0; n < 4; ++n)
        acc[4 + m][n] = __builtin_amdgcn_mfma_f32_16x16x32_bf16(
            af[m], bv[n], acc[4 + m][n], 0, 0, 0);
    __builtin_amdgcn_s_setprio(0);

    // K-tile boundary: counted wait — next tile's 4 oldest loads must have
    // landed; the 4 newest (tile tau+2) stay in flight.  Never vmcnt(0)
    // except when no further stages were issued (tail).
    if (tau < nt - 1) {
      if (st) asm volatile("s_waitcnt vmcnt(4)" ::: "memory");
      else    asm volatile("s_waitcnt vmcnt(0)" ::: "memory");
      __builtin_amdgcn_s_barrier();
    }
    buf = (buf == 2) ? 0 : buf + 1;
    sbuf = (sbuf == 2) ? 0 : sbuf + 1;
  }

  const long cOff = (long)z * sC1;
  const int colB = bx * 256 + wn * 64;
  const int rowBase = by * 256 + wm * 128;
#pragma unroll
  for (int i = 0; i < 8; ++i) {
#pragma unroll
    for (int j = 0; j < 4; ++j) {
#pragma unroll
      for (int r = 0; r < 4; ++r) {
        const int row = rowBase + i * 16 + quad * 4 + r;
        const int col = colB + j * 16 + laneM;
        const long idx = cOff + (long)row * ldc + col;
        float v = acc[i][j][r];
        if (EPI == 0) {
          ((u16*)Cv)[idx] = f2b(v);
        } else {
          ((float*)Cv)[idx] =
              (z == 0) ? v + bias[col] + resid[(long)row * ldc + col] : v;
        }
      }
    }
  }
}

// ---------------------------------------------------------------------------
// Convert 7 fp32 2048x2048 tensors -> bf16, dsts contiguous from dst base.
// ---------------------------------------------------------------------------
__global__ __launch_bounds__(256) void convert7(
    const float* __restrict__ s0, const float* __restrict__ s1,
    const float* __restrict__ s2, const float* __restrict__ s3,
    const float* __restrict__ s4, const float* __restrict__ s5,
    const float* __restrict__ s6, u16* __restrict__ dst) {
  long idx = (long)blockIdx.x * 256 + threadIdx.x;  // 0 .. 7*1048576-1
  int seg = (int)(idx >> 20);
  long off = (idx & 1048575) << 2;
  const float* s;
  switch (seg) {
    case 0: s = s0; break; case 1: s = s1; break; case 2: s = s2; break;
    case 3: s = s3; break; case 4: s = s4; break; case 5: s = s5; break;
    default: s = s6;
  }
  float4 v = *(const float4*)(s + off);
  ushort4 o;
  o.x = f2b(v.x); o.y = f2b(v.y); o.z = f2b(v.z); o.w = f2b(v.w);
  *(ushort4*)(dst + (long)seg * 4194304 + off) = o;
}

// cs_seq[h,m]: scan over heads collecting the PRE-update carry.
// part[h*256+m] holds sum over (b,l) of kv (from GEMM-epilogue atomics).
__global__ __launch_bounds__(256) void cs_kernel(
    const float* __restrict__ part, float* __restrict__ cs,
    const float* __restrict__ alphaP, const float* __restrict__ betaP) {
  int m = threadIdx.x;
  float alpha = *alphaP, beta = *betaP;
  float c = 0.f;
  for (int h = 0; h < 8; ++h) {
    cs[h * 256 + m] = c;
    c = beta * c + alpha * (part[h * 256 + m] * (1.0f / 2048.0f));
  }
}

// pq = phi(Q * (cs + alpha*(kv - cs))), pk = phi(K); phi(x)=x>0?x+1:exp(x)
__global__ __launch_bounds__(256) void pqpk_kernel(
    const u16* __restrict__ Qp, const u16* __restrict__ Kp,
    const u16* __restrict__ kv, const float* __restrict__ cs,
    const float* __restrict__ alphaP, u16* __restrict__ pq,
    u16* __restrict__ pk) {
  long idx = (long)blockIdx.x * 256 + threadIdx.x;  // (b,h,l,d) packed
  int d = idx & 255, l = (int)((idx >> 8) & 255), h = (int)((idx >> 16) & 7),
      b = (int)(idx >> 19);
  float alpha = *alphaP;
  long pidx = ((long)(b * 256 + l)) * 2048 + h * 256 + d;
  float Qv = b2f(Qp[pidx]);
  float kvv = b2f(kv[idx]);  // kv layout (b,h,l,m) == idx packing
  float csv = cs[h * 256 + d];
  float qm = Qv * (csv + alpha * (kvv - csv));
  pq[idx] = f2b(qm > 0.f ? qm + 1.f : expf(qm));
  float Kv = b2f(Kp[pidx]);
  pk[idx] = f2b(Kv > 0.f ? Kv + 1.f : expf(Kv));
}

// Vt[b,h,d,j] = V[b*256+j, h*256+d]  (per-(b,h) 256x256 transpose)
__global__ __launch_bounds__(256) void vtrans_kernel(const u16* __restrict__ Vp,
                                                     u16* __restrict__ Vt) {
  __shared__ u16 tile[32][33];
  int z = blockIdx.z, b = z >> 3, h = z & 7;
  int jT = blockIdx.x * 32, dT = blockIdx.y * 32;
  int tx = threadIdx.x, ty = threadIdx.y;  // (32, 8)
#pragma unroll
  for (int ii = 0; ii < 4; ++ii) {
    int j = jT + ty + ii * 8, d = dT + tx;
    tile[ty + ii * 8][tx] = Vp[(long)(b * 256 + j) * 2048 + h * 256 + d];
  }
  __syncthreads();
#pragma unroll
  for (int ii = 0; ii < 4; ++ii) {
    int d = dT + ty + ii * 8, j = jT + tx;
    Vt[(long)z * 65536 + d * 256 + j] = tile[tx][ty + ii * 8];
  }
}

// LayerNorm over rows of 2048; input = x0 + x1 (split-K partials).
__global__ __launch_bounds__(256) void ln_kernel(
    const float* __restrict__ x0, const float* __restrict__ x1,
    const float* __restrict__ g, const float* __restrict__ bb,
    float* __restrict__ out) {
  int row = blockIdx.x, t = threadIdx.x;
  const float4* xr0 = (const float4*)(x0 + (long)row * 2048);
  const float4* xr1 = (const float4*)(x1 + (long)row * 2048);
  float4 a0 = xr0[t], b0 = xr1[t], a1 = xr0[t + 256], b1 = xr1[t + 256];
  float4 v0, v1;
  v0.x = a0.x + b0.x; v0.y = a0.y + b0.y; v0.z = a0.z + b0.z; v0.w = a0.w + b0.w;
  v1.x = a1.x + b1.x; v1.y = a1.y + b1.y; v1.z = a1.z + b1.z; v1.w = a1.w + b1.w;
  float s = v0.x + v0.y + v0.z + v0.w + v1.x + v1.y + v1.z + v1.w;
  float ss = v0.x * v0.x + v0.y * v0.y + v0.z * v0.z + v0.w * v0.w +
             v1.x * v1.x + v1.y * v1.y + v1.z * v1.z + v1.w * v1.w;
  for (int o = 32; o; o >>= 1) { s += __shfl_xor(s, o); ss += __shfl_xor(ss, o); }
  __shared__ float a1s[4], a2s[4];
  int wave = t >> 6, lane = t & 63;
  if (lane == 0) { a1s[wave] = s; a2s[wave] = ss; }
  __syncthreads();
  s = a1s[0] + a1s[1] + a1s[2] + a1s[3];
  ss = a2s[0] + a2s[1] + a2s[2] + a2s[3];
  float mu = s * (1.f / 2048.f);
  float var = ss * (1.f / 2048.f) - mu * mu;
  float rstd = rsqrtf(var + 1e-5f);
  const float4* g4 = (const float4*)g;
  const float4* b4 = (const float4*)bb;
  float4* orow = (float4*)(out + (long)row * 2048);
  float4 gg = g4[t], bv = b4[t], r;
  r.x = (v0.x - mu) * rstd * gg.x + bv.x;
  r.y = (v0.y - mu) * rstd * gg.y + bv.y;
  r.z = (v0.z - mu) * rstd * gg.z + bv.z;
  r.w = (v0.w - mu) * rstd * gg.w + bv.w;
  orow[t] = r;
  gg = g4[t + 256]; bv = b4[t + 256];
  r.x = (v1.x - mu) * rstd * gg.x + bv.x;
  r.y = (v1.y - mu) * rstd * gg.y + bv.y;
  r.z = (v1.z - mu) * rstd * gg.z + bv.z;
  r.w = (v1.w - mu) * rstd * gg.w + bv.w;
  orow[t + 256] = r;
}

extern "C" void kernel_launch(void* const* d_in, const int* in_sizes, int n_in,
                              void* d_out, int out_size, void* d_ws,
                              size_t ws_size, hipStream_t stream) {
  const float* query = (const float*)d_in[0];
  const float* key = (const float*)d_in[1];
  const float* value = (const float*)d_in[2];
  const float* Wq = (const float*)d_in[3];
  const float* Wk = (const float*)d_in[4];
  const float* Wv = (const float*)d_in[5];
  const float* Wo = (const float*)d_in[6];
  const float* bo = (const float*)d_in[7];
  const float* ln_g = (const float*)d_in[8];
  const float* ln_b = (const float*)d_in[9];
  const float* alphaP = (const float*)d_in[10];
  const float* betaP = (const float*)d_in[11];

  char* ws = (char*)d_ws;
  const long SZ = 8388608;  // bytes of one 2048x2048 bf16 tensor
  u16* qb = (u16*)(ws);                // q,k,v bf16 (3*SZ); x1 aliases later
  u16* Wb = (u16*)(ws + 3 * SZ);       // Wq,Wk,Wv,Wo bf16 (4*SZ)
  u16* Qp = (u16*)(ws + 7 * SZ);       // Q,K,V projections bf16 (3*SZ)
  u16* kvb = (u16*)(ws + 10 * SZ);     // kv bf16 (SZ); later aliased by Ab
  u16* pq = (u16*)(ws + 12 * SZ);      // (SZ)
  u16* pk = (u16*)(ws + 13 * SZ);      // (SZ)
  u16* Vt = (u16*)(ws + 14 * SZ);      // (SZ)
  u16* attnb = (u16*)(ws + 15 * SZ);   // (SZ)
  u16* Ab = (u16*)(ws + 10 * SZ);      // aliases kvb (dead after pqpk)
  float* x0 = (float*)(ws + 12 * SZ);  // 16MB, aliases pq/pk (dead after A GEMM)
  float* x1 = (float*)(ws);            // 16MB, aliases qb..vb (dead after proj)
  float* part = (float*)(ws + 16 * SZ);            // 8 KB (atomic-accumulated)
  float* cs = (float*)(ws + 16 * SZ + 16384);      // 8 KB

  u16* Kp = Qp + 4194304;
  u16* Vp = Qp + 8388608;
  u16* Wob = Wb + 3 * 4194304;

  // 0. zero the cs partial-sum accumulator (d_ws is re-poisoned every call)
  hipMemsetAsync(part, 0, 8 * 256 * sizeof(float), stream);

  // 1. fp32 -> bf16 converts (7 tensors)
  convert7<<<28672, 256, 0, stream>>>(query, key, value, Wq, Wk, Wv, Wo, qb);

  // 2. Q/K/V projections: 256^2-tile counted-vmcnt GEMM, z=0..2 batched.
  //    Grid 8x8x3 flattened to 192 (XCD-chunk-swizzled in kernel).
  gemm256<0><<<dim3(192, 1, 1), 512, 0, stream>>>(
      qb, 2048, 4194304L, Wb, 2048, 4194304L, (void*)Qp, 2048, 4194304L,
      2048, nullptr, nullptr);

  // 3. kv[b,h,l,m] = sum_d K[b,h,l,d] V[b,h,m,d] (64 batches, bf16 out)
  //    + fused column sums into part[h*256+m] via atomics
  gemm_bt<1, 64><<<dim3(2, 2, 64), 256, 0, stream>>>(
      Kp, 2048, 524288L, 256L, Vp, 2048, 524288L, 256L, (void*)kvb, 256,
      524288L, 65536L, 256, 8, nullptr, nullptr, part);

  // 4. cs scan over heads (head-means already in part)
  cs_kernel<<<1, 256, 0, stream>>>(part, cs, alphaP, betaP);

  // 5. pq = phi(Q*(cs+alpha*(kv-cs))), pk = phi(K)
  pqpk_kernel<<<16384, 256, 0, stream>>>(Qp, Kp, kvb, cs, alphaP, pq, pk);

  // 6. A = pq @ pk^T, causal-masked, bf16 (overwrites kv region).
  //    Fully-masked block (x=1,y=0) skipped: 3 xy-blocks per batch.
  gemm_bt<2, 64><<<dim3(3, 1, 64), 256, 0, stream>>>(
      pq, 256, 524288L, 65536L, pk, 256, 524288L, 65536L, (void*)Ab, 256,
      524288L, 65536L, 256, 8, nullptr, nullptr, nullptr);

  // 7. V transpose per (b,h): Vt[d,j] = V[j,d]
  vtrans_kernel<<<dim3(8, 8, 64), dim3(32, 8), 0, stream>>>(Vp, Vt);

  // 8. attn = (A @ V) / den, den fused from A-fragments, K clamped causally
  gemm_bt<3, 64><<<dim3(2, 2, 64), 256, 0, stream>>>(
      Ab, 256, 524288L, 65536L, Vt, 256, 524288L, 65536L, (void*)attnb, 2048,
      524288L, 256L, 256, 8, nullptr, nullptr, nullptr);

  // 9. x = attn @ Wo^T (+ bo + query on z=0), split-K=2, 256^2 tiles.
  //    Grid 8x8x2 flattened to 128. sC1 = x1 - x0 = -12*SZ/4 floats.
  gemm256<4><<<dim3(128, 1, 1), 512, 0, stream>>>(
      attnb, 2048, 1024L, Wob, 2048, 1024L, (void*)x0, 2048, -25165824L,
      1024, bo, query);

  // 10. LayerNorm(x0 + x1) -> d_out
  ln_kernel<<<2048, 256, 0, stream>>>(x0, x1, ln_g, ln_b, (float*)d_out);
}

// Round 2
// 335.003 us; speedup vs baseline: 1.0273x; 1.0273x over previous
//
#include <hip/hip_runtime.h>
#include <hip/hip_bf16.h>

using u16 = unsigned short;

typedef __bf16 bf16x8 __attribute__((ext_vector_type(8)));
typedef float  f32x4  __attribute__((ext_vector_type(4)));

__device__ __forceinline__ float b2f(u16 u) {
  union { unsigned u; float f; } v; v.u = ((unsigned)u) << 16; return v.f;
}
__device__ __forceinline__ u16 f2b(float f) {
  union { float f; unsigned u; } v; v.f = f;
  unsigned r = v.u + 0x7fffu + ((v.u >> 16) & 1u);
  return (u16)(r >> 16);
}

// async global->LDS, 16B per lane. LDS dest must be uniform base + lane*16.
__device__ __forceinline__ void gld_lds16(const void* g, void* l) {
  __builtin_amdgcn_global_load_lds(
      (__attribute__((address_space(1))) void*)(unsigned long long)(g),
      (__attribute__((address_space(3))) void*)(unsigned long long)(l),
      16, 0, 0);
}

// ---------------------------------------------------------------------------
// Generic NT GEMM: C[m,n] = sum_k A[m,k] * B[n,k], bf16 in, fp32 acc.
// Block tile 128x128, 4 waves (2x2), wave = 4x4 of 16x16x32 MFMA.
// Retained for the small per-(b,h) GEMMs (kv / causal-A / A@V, EPI 1..3).
// ---------------------------------------------------------------------------
template <int EPI, int BK>
__global__ __launch_bounds__(256) void gemm_bt(
    const u16* __restrict__ A, int lda, long sA1, long sA2,
    const u16* __restrict__ B, int ldb, long sB1, long sB2,
    void* __restrict__ Cv, int ldc, long sC1, long sC2,
    int K, int HDIV,
    const float* __restrict__ bias, const float* __restrict__ resid,
    float* __restrict__ partOut) {
  __shared__ __align__(16) u16 lds[2 * 128 * BK];
  __shared__ float denS[128];
  const int t = threadIdx.x;
  const int lane = t & 63;
  const int wave = t >> 6;
  const int wm = wave >> 1, wn = wave & 1;
  const int laneM = lane & 15, quad = lane >> 4;
  const int zb = blockIdx.z / HDIV, zh = blockIdx.z % HDIV;

  int bx = blockIdx.x, by = blockIdx.y;
  if (EPI == 2) { by = (bx >= 1) ? 1 : 0; bx = (bx == 2) ? 1 : 0; }
  const int kEnd = (EPI == 3) ? ((by + 1) * 128 < K ? (by + 1) * 128 : K) : K;

  const u16* Abase = A + zb * sA1 + zh * sA2 + (long)by * 128 * lda;
  const u16* Bbase = B + zb * sB1 + zh * sB2 + (long)bx * 128 * ldb;

  constexpr int STEPS = BK / 16;   // staging steps per operand (2048 elem each)
  constexpr int RPS = 2048 / BK;   // rows per staging step
  constexpr int KK = BK / 32;      // MFMA k-steps per LDS tile
  const int sRow = (BK == 64) ? (t >> 3) : (t >> 2);
  const int sg = (BK == 64) ? (t & 7) : (t & 3);
  const int swz = (BK == 64) ? (sg ^ (sRow & 7)) : (sg ^ ((sRow >> 1) & 3));
  const int sc = swz * 8;  // swizzled global k-chunk offset (elems)

  f32x4 acc[4][4];
#pragma unroll
  for (int i = 0; i < 4; ++i)
#pragma unroll
    for (int j = 0; j < 4; ++j) acc[i][j] = (f32x4){0.f, 0.f, 0.f, 0.f};
  float dsum[4] = {0.f, 0.f, 0.f, 0.f};

  for (int k0 = 0; k0 < kEnd; k0 += BK) {
#pragma unroll
    for (int p = 0; p < STEPS; ++p)
      gld_lds16(Abase + (long)(p * RPS + sRow) * lda + k0 + sc,
                &lds[p * 2048 + t * 8]);
#pragma unroll
    for (int p = 0; p < STEPS; ++p)
      gld_lds16(Bbase + (long)(p * RPS + sRow) * ldb + k0 + sc,
                &lds[128 * BK + p * 2048 + t * 8]);
    __syncthreads();  // drains vmcnt(0): LDS staging complete
    bf16x8 af[KK][4], bfv[KK][4];
#pragma unroll
    for (int kk = 0; kk < KK; ++kk) {
      int perm8;
      if (BK == 64) perm8 = ((kk * 4 + quad) ^ (laneM & 7)) * 8;
      else          perm8 = (quad ^ ((laneM >> 1) & 3)) * 8;
#pragma unroll
      for (int i = 0; i < 4; ++i) {
        af[kk][i] = *(const bf16x8*)&lds[(wm * 64 + i * 16 + laneM) * BK + perm8];
        bfv[kk][i] =
            *(const bf16x8*)&lds[128 * BK + (wn * 64 + i * 16 + laneM) * BK + perm8];
      }
    }
    if (EPI == 3) {  // rowsum of A from fragments (den; mask is pre-applied)
#pragma unroll
      for (int kk = 0; kk < KK; ++kk)
#pragma unroll
        for (int i = 0; i < 4; ++i) {
          union { bf16x8 v; u16 s[8]; } u; u.v = af[kk][i];
          float ds = 0.f;
#pragma unroll
          for (int e = 0; e < 8; ++e) ds += b2f(u.s[e]);
          dsum[i] += ds;
        }
    }
#pragma unroll
    for (int kk = 0; kk < KK; ++kk)
#pragma unroll
      for (int i = 0; i < 4; ++i)
#pragma unroll
        for (int j = 0; j < 4; ++j)
          acc[i][j] = __builtin_amdgcn_mfma_f32_16x16x32_bf16(
              af[kk][i], bfv[kk][j], acc[i][j], 0, 0, 0);
    __syncthreads();  // all waves done reading before next stage
  }

  if (EPI == 3) {
#pragma unroll
    for (int i = 0; i < 4; ++i) {
      float s = dsum[i];
      s += __shfl_xor(s, 16);
      s += __shfl_xor(s, 32);
      if (wn == 0 && quad == 0)
        denS[wm * 64 + i * 16 + laneM] = fmaxf(s, 1e-8f);
    }
    __syncthreads();
  }

  if (EPI == 1) {  // column sums of tile -> part[zh*256 + col] (cs fusion)
#pragma unroll
    for (int j = 0; j < 4; ++j) {
      float s = 0.f;
#pragma unroll
      for (int i = 0; i < 4; ++i)
#pragma unroll
        for (int r = 0; r < 4; ++r) s += acc[i][j][r];
      s += __shfl_xor(s, 16);
      s += __shfl_xor(s, 32);
      if (quad == 0)
        atomicAdd(&partOut[zh * 256 + bx * 128 + wn * 64 + j * 16 + laneM], s);
    }
  }

  const long cOff = zb * sC1 + zh * sC2;
  const int colB = bx * 128 + wn * 64;
#pragma unroll
  for (int i = 0; i < 4; ++i) {
#pragma unroll
    for (int j = 0; j < 4; ++j) {
#pragma unroll
      for (int r = 0; r < 4; ++r) {
        const int lrow = wm * 64 + i * 16 + quad * 4 + r;  // row within block
        const int row = by * 128 + lrow;                   // within-batch row
        const int col = colB + j * 16 + laneM;             // within-batch col
        const long idx = cOff + (long)row * ldc + col;
        float v = acc[i][j][r];
        if (EPI == 0 || EPI == 1) {
          ((u16*)Cv)[idx] = f2b(v);
        } else if (EPI == 2) {
          ((u16*)Cv)[idx] = f2b(col <= row ? v : 0.0f);
        } else if (EPI == 3) {
          ((u16*)Cv)[idx] = f2b(v / denS[lrow]);
        } else {
          ((float*)Cv)[idx] =
              (zb == 0) ? v + bias[col] + resid[(long)row * ldc + col] : v;
        }
      }
    }
  }
}

// ---------------------------------------------------------------------------
// One K-tile (BK=32) of the 256x256 pipelined GEMM.  la/lb: buffers being
// consumed (tile tau); sa/sb: buffers being staged (tile tau+3).  All four
// are DISTINCT __shared__ objects passed as compile-time-known pointers so
// alias analysis can prove the async global_load_lds writes never touch the
// ds_read sources -> no compiler-inserted vmcnt(0) drain per phase (the R1
// defect: runtime-indexed lds[buf] forced a full-latency drain every phase).
// Two phases: {8 ds_read, stage A(tau+3), bar, lgkm(0), 16 MFMA, bar} then
// {4 ds_read, stage B(tau+3), bar, lgkm(0), 16 MFMA}.  Boundary: counted
// vmcnt(8) (tiles tau+2, tau+3 in flight; tau+1's loads — issued ~2 tiles
// ago — must have landed) + barrier.  vmcnt(4)/(0) only in the 2-tile tail.
// ---------------------------------------------------------------------------
__device__ __forceinline__ void g256_tile(
    const u16* __restrict__ la, const u16* __restrict__ lb,
    u16* __restrict__ sa, u16* __restrict__ sb, int tau, int nt,
    const u16* AgR0, const u16* AgR1, const u16* BgR0, const u16* BgR1,
    int rowA, int rowB, int rg, int t, f32x4 (&acc)[8][4]) {
  const bool st = (tau + 3) < nt;
  const int ks = (tau + 3) << 5;
  bf16x8 af[4], bv[4];
#pragma unroll
  for (int m = 0; m < 4; ++m)
    af[m] = *(const bf16x8*)&la[(rowA + m * 16) * 32 + rg];
#pragma unroll
  for (int n = 0; n < 4; ++n)
    bv[n] = *(const bf16x8*)&lb[(rowB + n * 16) * 32 + rg];
  if (st) {
    gld_lds16(AgR0 + ks, &sa[t * 8]);
    gld_lds16(AgR1 + ks, &sa[4096 + t * 8]);
  }
  __builtin_amdgcn_s_barrier();
  asm volatile("s_waitcnt lgkmcnt(0)" ::: "memory");
  __builtin_amdgcn_s_setprio(1);
#pragma unroll
  for (int m = 0; m < 4; ++m)
#pragma unroll
    for (int n = 0; n < 4; ++n)
      acc[m][n] = __builtin_amdgcn_mfma_f32_16x16x32_bf16(af[m], bv[n],
                                                          acc[m][n], 0, 0, 0);
  __builtin_amdgcn_s_setprio(0);
  __builtin_amdgcn_s_barrier();
#pragma unroll
  for (int m = 0; m < 4; ++m)
    af[m] = *(const bf16x8*)&la[(rowA + 64 + m * 16) * 32 + rg];
  if (st) {
    gld_lds16(BgR0 + ks, &sb[t * 8]);
    gld_lds16(BgR1 + ks, &sb[4096 + t * 8]);
  }
  __builtin_amdgcn_s_barrier();
  asm volatile("s_waitcnt lgkmcnt(0)" ::: "memory");
  __builtin_amdgcn_s_setprio(1);
#pragma unroll
  for (int m = 0; m < 4; ++m)
#pragma unroll
    for (int n = 0; n < 4; ++n)
      acc[4 + m][n] = __builtin_amdgcn_mfma_f32_16x16x32_bf16(
          af[m], bv[n], acc[4 + m][n], 0, 0, 0);
  __builtin_amdgcn_s_setprio(0);
  if (tau < nt - 1) {
    if (tau + 3 < nt)
      asm volatile("s_waitcnt vmcnt(8)" ::: "memory");
    else if (tau + 2 < nt)
      asm volatile("s_waitcnt vmcnt(4)" ::: "memory");
    else
      asm volatile("s_waitcnt vmcnt(0)" ::: "memory");
    __builtin_amdgcn_s_barrier();
  }
}

// ---------------------------------------------------------------------------
// 256x256 NT GEMM, counted-vmcnt pipeline, STATIC quad-buffered LDS.
// 512 threads = 8 waves (2 M x 4 N); per-wave 128x64 output = 8x4 16x16 frags.
// 4 separate 16KB buffers per operand (128 KB LDS, 1 block/CU), prefetch
// distance 3 tiles, main loop statically unrolled x4 (nt = 64 or 32, %4==0).
// Swizzle identical to gemm_bt BK=32 (proven): stage chunk g of row r holds
// global chunk g^((r>>1)&3); read granule quad^((laneM>>1)&3); 0 conflicts.
// Grid: flat 8*8*Z, bijective chunked XCD swizzle (grid %8==0).
// EPI 0: bf16 out (proj). EPI 4: fp32 out, z==0 adds bias+resid (Wo splitK).
// ---------------------------------------------------------------------------
template <int EPI>
__global__ __launch_bounds__(512) void gemm256(
    const u16* __restrict__ A, int lda, long sA1,
    const u16* __restrict__ B, int ldb, long sB1,
    void* __restrict__ Cv, int ldc, long sC1, int K,
    const float* __restrict__ bias, const float* __restrict__ resid) {
  __shared__ __align__(16) u16 A0[8192], A1[8192], A2[8192], A3[8192];
  __shared__ __align__(16) u16 B0[8192], B1[8192], B2[8192], B3[8192];
  const int t = threadIdx.x;
  const int lane = t & 63, wave = t >> 6;
  const int wm = wave >> 2, wn = wave & 3;
  const int laneM = lane & 15, quad = lane >> 4;

  const int cpx = gridDim.x >> 3;                      // blocks per XCD chunk
  const int id2 = (blockIdx.x & 7) * cpx + (blockIdx.x >> 3);
  const int bx = id2 & 7, by = (id2 >> 3) & 7, z = id2 >> 6;

  const u16* Ag = A + (long)z * sA1 + (long)by * 256 * lda;
  const u16* Bg = B + (long)z * sB1 + (long)bx * 256 * ldb;

  const int nt = K >> 5;                               // K-tiles of 32
  const int rg = (quad ^ ((laneM >> 1) & 3)) * 8;      // read-granule offset
  const int rowA = wm * 128 + laneM;
  const int rowB = wn * 64 + laneM;

  // staging addresses: thread t covers chunks t and 512+t of each tile
  const int sRow0 = t >> 2, sRow1 = (512 + t) >> 2;
  const int sc0 = (((t) & 3) ^ ((sRow0 >> 1) & 3)) * 8;
  const int sc1 = (((512 + t) & 3) ^ ((sRow1 >> 1) & 3)) * 8;
  const u16* AgR0 = Ag + (long)sRow0 * lda + sc0;
  const u16* AgR1 = Ag + (long)sRow1 * lda + sc1;
  const u16* BgR0 = Bg + (long)sRow0 * ldb + sc0;
  const u16* BgR1 = Bg + (long)sRow1 * ldb + sc1;

  f32x4 acc[8][4];
#pragma unroll
  for (int i = 0; i < 8; ++i)
#pragma unroll
    for (int j = 0; j < 4; ++j) acc[i][j] = (f32x4){0.f, 0.f, 0.f, 0.f};

  // prologue: stage tiles 0,1,2 into bufs 0,1,2 (12 loads/thread-pair total);
  // wait only for tile 0 (oldest 4), keep 8 in flight.
  gld_lds16(AgR0, &A0[t * 8]);      gld_lds16(AgR1, &A0[4096 + t * 8]);
  gld_lds16(BgR0, &B0[t * 8]);      gld_lds16(BgR1, &B0[4096 + t * 8]);
  gld_lds16(AgR0 + 32, &A1[t * 8]); gld_lds16(AgR1 + 32, &A1[4096 + t * 8]);
  gld_lds16(BgR0 + 32, &B1[t * 8]); gld_lds16(BgR1 + 32, &B1[4096 + t * 8]);
  gld_lds16(AgR0 + 64, &A2[t * 8]); gld_lds16(AgR1 + 64, &A2[4096 + t * 8]);
  gld_lds16(BgR0 + 64, &B2[t * 8]); gld_lds16(BgR1 + 64, &B2[4096 + t * 8]);
  asm volatile("s_waitcnt vmcnt(8)" ::: "memory");
  __builtin_amdgcn_s_barrier();

  for (int tau = 0; tau < nt; tau += 4) {
    g256_tile(A0, B0, A3, B3, tau, nt, AgR0, AgR1, BgR0, BgR1, rowA, rowB,
              rg, t, acc);
    g256_tile(A1, B1, A0, B0, tau + 1, nt, AgR0, AgR1, BgR0, BgR1, rowA,
              rowB, rg, t, acc);
    g256_tile(A2, B2, A1, B1, tau + 2, nt, AgR0, AgR1, BgR0, BgR1, rowA,
              rowB, rg, t, acc);
    g256_tile(A3, B3, A2, B2, tau + 3, nt, AgR0, AgR1, BgR0, BgR1, rowA,
              rowB, rg, t, acc);
  }

  const long cOff = (long)z * sC1;
  const int colB = bx * 256 + wn * 64;
  const int rowBase = by * 256 + wm * 128;
#pragma unroll
  for (int i = 0; i < 8; ++i) {
#pragma unroll
    for (int j = 0; j < 4; ++j) {
#pragma unroll
      for (int r = 0; r < 4; ++r) {
        const int row = rowBase + i * 16 + quad * 4 + r;
        const int col = colB + j * 16 + laneM;
        const long idx = cOff + (long)row * ldc + col;
        float v = acc[i][j][r];
        if (EPI == 0) {
          ((u16*)Cv)[idx] = f2b(v);
        } else {
          ((float*)Cv)[idx] =
              (z == 0) ? v + bias[col] + resid[(long)row * ldc + col] : v;
        }
      }
    }
  }
}

// ---------------------------------------------------------------------------
// Convert 7 fp32 2048x2048 tensors -> bf16, dsts contiguous from dst base.
// ---------------------------------------------------------------------------
__global__ __launch_bounds__(256) void convert7(
    const float* __restrict__ s0, const float* __restrict__ s1,
    const float* __restrict__ s2, const float* __restrict__ s3,
    const float* __restrict__ s4, const float* __restrict__ s5,
    const float* __restrict__ s6, u16* __restrict__ dst) {
  long idx = (long)blockIdx.x * 256 + threadIdx.x;  // 0 .. 7*1048576-1
  int seg = (int)(idx >> 20);
  long off = (idx & 1048575) << 2;
  const float* s;
  switch (seg) {
    case 0: s = s0; break; case 1: s = s1; break; case 2: s = s2; break;
    case 3: s = s3; break; case 4: s = s4; break; case 5: s = s5; break;
    default: s = s6;
  }
  float4 v = *(const float4*)(s + off);
  ushort4 o;
  o.x = f2b(v.x); o.y = f2b(v.y); o.z = f2b(v.z); o.w = f2b(v.w);
  *(ushort4*)(dst + (long)seg * 4194304 + off) = o;
}

// cs_seq[h,m]: scan over heads collecting the PRE-update carry.
// part[h*256+m] holds sum over (b,l) of kv (from GEMM-epilogue atomics).
__global__ __launch_bounds__(256) void cs_kernel(
    const float* __restrict__ part, float* __restrict__ cs,
    const float* __restrict__ alphaP, const float* __restrict__ betaP) {
  int m = threadIdx.x;
  float alpha = *alphaP, beta = *betaP;
  float c = 0.f;
  for (int h = 0; h < 8; ++h) {
    cs[h * 256 + m] = c;
    c = beta * c + alpha * (part[h * 256 + m] * (1.0f / 2048.0f));
  }
}

// pq = phi(Q * (cs + alpha*(kv - cs))), pk = phi(K); phi(x)=x>0?x+1:exp(x)
__global__ __launch_bounds__(256) void pqpk_kernel(
    const u16* __restrict__ Qp, const u16* __restrict__ Kp,
    const u16* __restrict__ kv, const float* __restrict__ cs,
    const float* __restrict__ alphaP, u16* __restrict__ pq,
    u16* __restrict__ pk) {
  long idx = (long)blockIdx.x * 256 + threadIdx.x;  // (b,h,l,d) packed
  int d = idx & 255, l = (int)((idx >> 8) & 255), h = (int)((idx >> 16) & 7),
      b = (int)(idx >> 19);
  float alpha = *alphaP;
  long pidx = ((long)(b * 256 + l)) * 2048 + h * 256 + d;
  float Qv = b2f(Qp[pidx]);
  float kvv = b2f(kv[idx]);  // kv layout (b,h,l,m) == idx packing
  float csv = cs[h * 256 + d];
  float qm = Qv * (csv + alpha * (kvv - csv));
  pq[idx] = f2b(qm > 0.f ? qm + 1.f : expf(qm));
  float Kv = b2f(Kp[pidx]);
  pk[idx] = f2b(Kv > 0.f ? Kv + 1.f : expf(Kv));
}

// Vt[b,h,d,j] = V[b*256+j, h*256+d]  (per-(b,h) 256x256 transpose)
__global__ __launch_bounds__(256) void vtrans_kernel(const u16* __restrict__ Vp,
                                                     u16* __restrict__ Vt) {
  __shared__ u16 tile[32][33];
  int z = blockIdx.z, b = z >> 3, h = z & 7;
  int jT = blockIdx.x * 32, dT = blockIdx.y * 32;
  int tx = threadIdx.x, ty = threadIdx.y;  // (32, 8)
#pragma unroll
  for (int ii = 0; ii < 4; ++ii) {
    int j = jT + ty + ii * 8, d = dT + tx;
    tile[ty + ii * 8][tx] = Vp[(long)(b * 256 + j) * 2048 + h * 256 + d];
  }
  __syncthreads();
#pragma unroll
  for (int ii = 0; ii < 4; ++ii) {
    int d = dT + ty + ii * 8, j = jT + tx;
    Vt[(long)z * 65536 + d * 256 + j] = tile[tx][ty + ii * 8];
  }
}

// LayerNorm over rows of 2048; input = x0 + x1 (split-K partials).
__global__ __launch_bounds__(256) void ln_kernel(
    const float* __restrict__ x0, const float* __restrict__ x1,
    const float* __restrict__ g, const float* __restrict__ bb,
    float* __restrict__ out) {
  int row = blockIdx.x, t = threadIdx.x;
  const float4* xr0 = (const float4*)(x0 + (long)row * 2048);
  const float4* xr1 = (const float4*)(x1 + (long)row * 2048);
  float4 a0 = xr0[t], b0 = xr1[t], a1 = xr0[t + 256], b1 = xr1[t + 256];
  float4 v0, v1;
  v0.x = a0.x + b0.x; v0.y = a0.y + b0.y; v0.z = a0.z + b0.z; v0.w = a0.w + b0.w;
  v1.x = a1.x + b1.x; v1.y = a1.y + b1.y; v1.z = a1.z + b1.z; v1.w = a1.w + b1.w;
  float s = v0.x + v0.y + v0.z + v0.w + v1.x + v1.y + v1.z + v1.w;
  float ss = v0.x * v0.x + v0.y * v0.y + v0.z * v0.z + v0.w * v0.w +
             v1.x * v1.x + v1.y * v1.y + v1.z * v1.z + v1.w * v1.w;
  for (int o = 32; o; o >>= 1) { s += __shfl_xor(s, o); ss += __shfl_xor(ss, o); }
  __shared__ float a1s[4], a2s[4];
  int wave = t >> 6, lane = t & 63;
  if (lane == 0) { a1s[wave] = s; a2s[wave] = ss; }
  __syncthreads();
  s = a1s[0] + a1s[1] + a1s[2] + a1s[3];
  ss = a2s[0] + a2s[1] + a2s[2] + a2s[3];
  float mu = s * (1.f / 2048.f);
  float var = ss * (1.f / 2048.f) - mu * mu;
  float rstd = rsqrtf(var + 1e-5f);
  const float4* g4 = (const float4*)g;
  const float4* b4 = (const float4*)bb;
  float4* orow = (float4*)(out + (long)row * 2048);
  float4 gg = g4[t], bv = b4[t], r;
  r.x = (v0.x - mu) * rstd * gg.x + bv.x;
  r.y = (v0.y - mu) * rstd * gg.y + bv.y;
  r.z = (v0.z - mu) * rstd * gg.z + bv.z;
  r.w = (v0.w - mu) * rstd * gg.w + bv.w;
  orow[t] = r;
  gg = g4[t + 256]; bv = b4[t + 256];
  r.x = (v1.x - mu) * rstd * gg.x + bv.x;
  r.y = (v1.y - mu) * rstd * gg.y + bv.y;
  r.z = (v1.z - mu) * rstd * gg.z + bv.z;
  r.w = (v1.w - mu) * rstd * gg.w + bv.w;
  orow[t + 256] = r;
}

extern "C" void kernel_launch(void* const* d_in, const int* in_sizes, int n_in,
                              void* d_out, int out_size, void* d_ws,
                              size_t ws_size, hipStream_t stream) {
  const float* query = (const float*)d_in[0];
  const float* key = (const float*)d_in[1];
  const float* value = (const float*)d_in[2];
  const float* Wq = (const float*)d_in[3];
  const float* Wk = (const float*)d_in[4];
  const float* Wv = (const float*)d_in[5];
  const float* Wo = (const float*)d_in[6];
  const float* bo = (const float*)d_in[7];
  const float* ln_g = (const float*)d_in[8];
  const float* ln_b = (const float*)d_in[9];
  const float* alphaP = (const float*)d_in[10];
  const float* betaP = (const float*)d_in[11];

  char* ws = (char*)d_ws;
  const long SZ = 8388608;  // bytes of one 2048x2048 bf16 tensor
  u16* qb = (u16*)(ws);                // q,k,v bf16 (3*SZ); x1 aliases later
  u16* Wb = (u16*)(ws + 3 * SZ);       // Wq,Wk,Wv,Wo bf16 (4*SZ)
  u16* Qp = (u16*)(ws + 7 * SZ);       // Q,K,V projections bf16 (3*SZ)
  u16* kvb = (u16*)(ws + 10 * SZ);     // kv bf16 (SZ); later aliased by Ab
  u16* pq = (u16*)(ws + 12 * SZ);      // (SZ)
  u16* pk = (u16*)(ws + 13 * SZ);      // (SZ)
  u16* Vt = (u16*)(ws + 14 * SZ);      // (SZ)
  u16* attnb = (u16*)(ws + 15 * SZ);   // (SZ)
  u16* Ab = (u16*)(ws + 10 * SZ);      // aliases kvb (dead after pqpk)
  float* x0 = (float*)(ws + 12 * SZ);  // 16MB, aliases pq/pk (dead after A GEMM)
  float* x1 = (float*)(ws);            // 16MB, aliases qb..vb (dead after proj)
  float* part = (float*)(ws + 16 * SZ);            // 8 KB (atomic-accumulated)
  float* cs = (float*)(ws + 16 * SZ + 16384);      // 8 KB

  u16* Kp = Qp + 4194304;
  u16* Vp = Qp + 8388608;
  u16* Wob = Wb + 3 * 4194304;

  // 0. zero the cs partial-sum accumulator (d_ws is re-poisoned every call)
  hipMemsetAsync(part, 0, 8 * 256 * sizeof(float), stream);

  // 1. fp32 -> bf16 converts (7 tensors)
  convert7<<<28672, 256, 0, stream>>>(query, key, value, Wq, Wk, Wv, Wo, qb);

  // 2. Q/K/V projections: 256^2-tile counted-vmcnt GEMM, z=0..2 batched.
  //    Grid 8x8x3 flattened to 192 (XCD-chunk-swizzled in kernel).
  gemm256<0><<<dim3(192, 1, 1), 512, 0, stream>>>(
      qb, 2048, 4194304L, Wb, 2048, 4194304L, (void*)Qp, 2048, 4194304L,
      2048, nullptr, nullptr);

  // 3. kv[b,h,l,m] = sum_d K[b,h,l,d] V[b,h,m,d] (64 batches, bf16 out)
  //    + fused column sums into part[h*256+m] via atomics
  gemm_bt<1, 64><<<dim3(2, 2, 64), 256, 0, stream>>>(
      Kp, 2048, 524288L, 256L, Vp, 2048, 524288L, 256L, (void*)kvb, 256,
      524288L, 65536L, 256, 8, nullptr, nullptr, part);

  // 4. cs scan over heads (head-means already in part)
  cs_kernel<<<1, 256, 0, stream>>>(part, cs, alphaP, betaP);

  // 5. pq = phi(Q*(cs+alpha*(kv-cs))), pk = phi(K)
  pqpk_kernel<<<16384, 256, 0, stream>>>(Qp, Kp, kvb, cs, alphaP, pq, pk);

  // 6. A = pq @ pk^T, causal-masked, bf16 (overwrites kv region).
  //    Fully-masked block (x=1,y=0) skipped: 3 xy-blocks per batch.
  gemm_bt<2, 64><<<dim3(3, 1, 64), 256, 0, stream>>>(
      pq, 256, 524288L, 65536L, pk, 256, 524288L, 65536L, (void*)Ab, 256,
      524288L, 65536L, 256, 8, nullptr, nullptr, nullptr);

  // 7. V transpose per (b,h): Vt[d,j] = V[j,d]
  vtrans_kernel<<<dim3(8, 8, 64), dim3(32, 8), 0, stream>>>(Vp, Vt);

  // 8. attn = (A @ V) / den, den fused from A-fragments, K clamped causally
  gemm_bt<3, 64><<<dim3(2, 2, 64), 256, 0, stream>>>(
      Ab, 256, 524288L, 65536L, Vt, 256, 524288L, 65536L, (void*)attnb, 2048,
      524288L, 256L, 256, 8, nullptr, nullptr, nullptr);

  // 9. x = attn @ Wo^T (+ bo + query on z=0), split-K=2, 256^2 tiles.
  //    Grid 8x8x2 flattened to 128. sC1 = x1 - x0 = -12*SZ/4 floats.
  gemm256<4><<<dim3(128, 1, 1), 512, 0, stream>>>(
      attnb, 2048, 1024L, Wob, 2048, 1024L, (void*)x0, 2048, -25165824L,
      1024, bo, query);

  // 10. LayerNorm(x0 + x1) -> d_out
  ln_kernel<<<2048, 256, 0, stream>>>(x0, x1, ln_g, ln_b, (float*)d_out);
}